// Round 16
// baseline (1125.251 us; speedup 1.0000x reference)
//
#include <hip/hip_runtime.h>
#include <hip/hip_bf16.h>

// Problem constants: B=4, C=64, H=W=64, HW=4096, P=64, Q=3 (CQ=192)
namespace {
constexpr int IMG    = 262144;   // 64*4096 elems per batch image
constexpr int MS     = 4;        // attention m-split
constexpr int PADIMG = 4356;     // 66*66 padded pixels
constexpr float LOG2E = 1.44269504088896340736f;
// workspace float offsets
constexpr int WBFO  = 0;         // fp16 weights: wbot[9][6][64][32], wout[9][6][64][32], wtop[6][64][32], wcen[6][64][32]
constexpr int XPADO = 122880;    // fp16 xp/up padded [b][ck 6][px 4356][32] (aliased: xp then up)
constexpr int TOPO  = 1795584;   // fp16 topT [b][m][p]
constexpr int CENO  = 2319872;   // fp16 cenT [b][n][p]
constexpr int BOTO  = 2844160;   // fp16 bot  [b][c][m]
constexpr int PVO   = 3368448;   // bf16 PV [4][b][n][c]
constexpr int MSO   = 5465600;   // m_s [s 4][b 4][group 256]
constexpr int ZSO   = 5469696;   // z_s
constexpr int BARO  = 5473792;   // grid-barrier counters: 4 x 64 ints (memset 0 pre-launch)
}

using half8v  = __attribute__((ext_vector_type(8))) _Float16;
using half4v  = __attribute__((ext_vector_type(4))) _Float16;
using short8v = __attribute__((ext_vector_type(8))) short;
typedef __attribute__((ext_vector_type(4))) float f32x4;

__device__ __forceinline__ short f2bf(float f) {
    __hip_bfloat16 h = __float2bfloat16(f);
    return *reinterpret_cast<short*>(&h);
}
__device__ __forceinline__ float bf2f(short s) {
    unsigned u = ((unsigned)(unsigned short)s) << 16;
    return __uint_as_float(u);
}

// Manual grid barrier: all 1024 blocks co-resident by construction
// (__launch_bounds__(256,4) caps VGPR<=128; LDS 27.7KB -> 4 blocks/CU x 256 CU).
// r15 lesson: poll must be a READ-ONLY device-scope atomic load. An
// atomicAdd(cnt,0) RMW poll serializes at the coherence point (~150us/barrier).
__device__ __forceinline__ void gbar(unsigned* cnt, int t) {
    __syncthreads();
    __threadfence();
    if (t == 0) {
        __hip_atomic_fetch_add(cnt, 1u, __ATOMIC_RELEASE, __HIP_MEMORY_SCOPE_AGENT);
        while (__hip_atomic_load(cnt, __ATOMIC_ACQUIRE, __HIP_MEMORY_SCOPE_AGENT) < 1024u)
            __builtin_amdgcn_s_sleep(8);
        __threadfence();
    }
    __syncthreads();
}

// x/u powers -> chunked padded fp16 [b][ck][px][32] incl. border zeroing.
__device__ __forceinline__ void pow_body(int bx2, int t, const float* __restrict__ src,
                                         _Float16* __restrict__ xpad, float* xs) {
    int b = bx2 >> 6, h = bx2 & 63;
    {   // zero this block's share of the pad border across all 6 chunk planes
        _Float16* base = xpad + (size_t)b * 6 * PADIMG * 32;
        int px[6];
        px[0] = (h + 1) * 66;
        px[1] = (h + 1) * 66 + 65;
        px[2] = h;
        px[3] = 65 * 66 + h;
        int npx = 4;
        if (h < 2) { px[4] = 64 + h; px[5] = 65 * 66 + 64 + h; npx = 6; }
        int pi = t / 24, ck = t % 24;
        if (pi < npx) {
            int cp = ck >> 2, q = ck & 3;
            half8v z = {0, 0, 0, 0, 0, 0, 0, 0};
            *(half8v*)&base[((size_t)cp * PADIMG + px[pi]) * 32 + q * 8] = z;
        }
    }
    #pragma unroll
    for (int it = 0; it < 16; ++it) {
        int idx = it * 256 + t;
        int ci = idx >> 6, wc = idx & 63;
        xs[ci * 65 + wc] = src[b * IMG + ci * 4096 + h * 64 + wc];
    }
    __syncthreads();
    _Float16* dst = xpad + ((size_t)b * 6 * PADIMG + (h + 1) * 66 + 1) * 32;
    #pragma unroll
    for (int it = 0; it < 6; ++it) {
        int u = it * 256 + t;
        int ck = u >> 8, within = u & 255;
        int px = within >> 2, q = within & 3;
        int k0 = ck * 32 + q * 8;
        int p = k0 >> 6, c0 = k0 & 63;
        half8v o;
        #pragma unroll
        for (int j = 0; j < 8; ++j) {
            float v = xs[(c0 + j) * 65 + px];
            float pw = (p == 0) ? v : ((p == 1) ? v * v : v * v * v);
            o[j] = (_Float16)pw;
        }
        *(half8v*)&dst[((size_t)ck * PADIMG + px) * 32 + q * 8] = o;
    }
}

// 3x3 SelfONN conv, full-K MFMA implicit GEMM, 32 oc/block, direct output+bias.
__device__ __forceinline__ void conv3d32(int bx, int t,
                                         const _Float16* __restrict__ src,
                                         const _Float16* __restrict__ wt,
                                         const float* __restrict__ bias,
                                         _Float16* __restrict__ dh_, float* __restrict__ df) {
    int lane = t & 63, w = t >> 6;
    int l16 = lane & 15, quad = lane >> 4;
    int oh = bx >> 8, mt = bx & 255;
    int b = mt >> 6, h = mt & 63;
    const _Float16* abase = src + ((size_t)b * 6 * PADIMG + (h + 1) * 66 + 1 + w * 16 + l16) * 32 + quad * 8;
    const _Float16* bbase = wt + (size_t)(oh * 32 + l16) * 32 + quad * 8;
    f32x4 acc[2];
    acc[0] = (f32x4){0.f, 0.f, 0.f, 0.f};
    acc[1] = (f32x4){0.f, 0.f, 0.f, 0.f};
    for (int tap = 0; tap < 9; ++tap) {
        int dh = tap / 3 - 1, dw = tap % 3 - 1;
        const _Float16* arow = abase + (dh * 66 + dw) * 32;
        const _Float16* brow = bbase + (size_t)tap * 6 * 2048;
        #pragma unroll
        for (int c6 = 0; c6 < 6; ++c6) {
            half8v afr  = *(const half8v*)&arow[(size_t)c6 * PADIMG * 32];
            half8v bfr0 = *(const half8v*)&brow[(size_t)c6 * 2048];
            half8v bfr1 = *(const half8v*)&brow[(size_t)c6 * 2048 + 512];
            acc[0] = __builtin_amdgcn_mfma_f32_16x16x32_f16(afr, bfr0, acc[0], 0, 0, 0);
            acc[1] = __builtin_amdgcn_mfma_f32_16x16x32_f16(afr, bfr1, acc[1], 0, 0, 0);
        }
    }
    #pragma unroll
    for (int nf = 0; nf < 2; ++nf) {
        int c = oh * 32 + nf * 16 + l16;
        float bv = bias[c];
        size_t oi = (size_t)b * 262144 + (size_t)c * 4096 + h * 64 + w * 16 + quad * 4;
        if (dh_) {
            half4v o;
            #pragma unroll
            for (int r = 0; r < 4; ++r) o[r] = (_Float16)(acc[nf][r] + bv);
            *(half4v*)&dh_[oi] = o;
        } else {
            float4 o = make_float4(acc[nf][0] + bv, acc[nf][1] + bv, acc[nf][2] + bv, acc[nf][3] + bv);
            *(float4*)&df[oi] = o;
        }
    }
}

__global__ __launch_bounds__(256, 4) void k_mega(
    const float* __restrict__ bw, const float* __restrict__ ow,
    const float* __restrict__ tw, const float* __restrict__ cw,
    const float* __restrict__ tb, const float* __restrict__ cb,
    const float* __restrict__ bbias, const float* __restrict__ ob,
    const float* __restrict__ x, float* ws, float* out) {
    __shared__ __align__(16) char smraw[27648];   // union: attn tiles / xs / us
    __shared__ float red8[8];
    int bx = blockIdx.x, t = threadIdx.x;
    unsigned* bar = (unsigned*)(ws + BARO);

    _Float16* wbf  = (_Float16*)(ws + WBFO);
    _Float16* wout = wbf + 110592;
    _Float16* xpad = (_Float16*)(ws + XPADO);    // also upad (aliased)
    _Float16* topb = (_Float16*)(ws + TOPO);
    _Float16* cenb = (_Float16*)(ws + CENO);
    _Float16* botb = (_Float16*)(ws + BOTO);

    // ======== Phase A: weight reorder (blocks 0..239, 4 elems/thread) +
    //                   x-powers (blocks 240..495) ========
    if (bx < 240) {
        #pragma unroll
        for (int rep = 0; rep < 4; ++rep) {
            int idx = bx * 256 + t + rep * 61440;   // < 245760
            if (idx < 221184) {
                // 3x3: w[o][(p*64+ci)*9+tap] -> wT[tap][ck][o][ki]
                int tsel = idx / 110592;
                int r    = idx - tsel * 110592;
                int tap  = r / 12288;
                int rr   = r - tap * 12288;
                int ck   = rr / 2048;
                int r2   = rr - ck * 2048;
                int o    = r2 >> 5;
                int ki   = r2 & 31;
                int k    = ck * 32 + ki;
                int p    = k >> 6, ci = k & 63;
                const float* src = tsel ? ow : bw;
                wbf[idx] = (_Float16)src[o * 1728 + (p * 64 + ci) * 9 + tap];
            } else {
                // 1x1: w[o][192] -> wT[ck][o][ki]; center pre-scaled by log2(e)
                int j = idx - 221184;
                int tsel = j / 12288;
                int rr   = j - tsel * 12288;
                int ck   = rr / 2048;
                int r2   = rr - ck * 2048;
                int o    = r2 >> 5;
                int ki   = r2 & 31;
                int k    = ck * 32 + ki;
                wbf[idx] = (_Float16)(tsel ? cw[o * 192 + k] * LOG2E : tw[o * 192 + k]);
            }
        }
    } else if (bx < 496) {
        pow_body(bx - 240, t, x, xpad, (float*)smraw);
    }
    gbar(bar, t);

    // ======== Phase B: conv3-bottom (blocks 0..511, fp16 out, oc-32) +
    //                   fused top/center 1x1 convs (blocks 512..1023) ========
    if (bx < 512) {
        conv3d32(bx, t, xpad, wbf /* wbot */, bbias, botb, nullptr);
    } else {
        int bx2 = bx - 512;
        int lane = t & 63, w = t >> 6;
        int l16 = lane & 15, quad = lane >> 4;
        int ot = bx2 >> 8, mt = bx2 & 255;
        int b = mt >> 6, h = mt & 63;
        const _Float16* wt   = wbf + (ot ? 233472 : 221184);   // wcen : wtop
        const float*    bias = ot ? cb : tb;
        _Float16*       dst  = (ot ? cenb : topb) + (size_t)b * IMG;
        const _Float16* abase = xpad + ((size_t)b * 6 * PADIMG + (h + 1) * 66 + 1 + w * 16 + l16) * 32 + quad * 8;
        const _Float16* bbase = wt + (size_t)l16 * 32 + quad * 8;
        f32x4 acc[4];
        #pragma unroll
        for (int nf = 0; nf < 4; ++nf) acc[nf] = (f32x4){0.f, 0.f, 0.f, 0.f};
        #pragma unroll
        for (int kc = 0; kc < 6; ++kc) {
            half8v afr = *(const half8v*)&abase[(size_t)kc * PADIMG * 32];
            #pragma unroll
            for (int nf = 0; nf < 4; ++nf) {
                half8v bfr = *(const half8v*)&bbase[(size_t)kc * 2048 + nf * 16 * 32];
                acc[nf] = __builtin_amdgcn_mfma_f32_16x16x32_f16(afr, bfr, acc[nf], 0, 0, 0);
            }
        }
        _Float16* dp = dst + (size_t)(h * 64 + w * 16) * 64;
        #pragma unroll
        for (int nf = 0; nf < 4; ++nf) {
            float bv = bias[nf * 16 + l16];
            if (ot) bv *= LOG2E;
            #pragma unroll
            for (int r = 0; r < 4; ++r)
                dp[(quad * 4 + r) * 64 + nf * 16 + l16] = (_Float16)(acc[nf][r] + bv);
        }
    }
    gbar(bar + 64, t);

    // ======== Phase C: fp16 MFMA flash attention (all 1024 blocks) ========
    {
        _Float16* ltop = (_Float16*)smraw;       // [m][p]
        _Float16* lbot = ltop + 64 * 72;         // [c][m]
        _Float16* lp   = lbot + 64 * 72;         // [n][m swizzled]; wave-private rows
        int lane = t & 63, w = t >> 6;
        int l16  = lane & 15, quad = lane >> 4;
        int st = bx & 63, b = (bx >> 6) & 3, s = bx >> 8;
        int n0 = st * 64;
        const _Float16* topg = topb + (size_t)b * IMG;
        const _Float16* ceng = cenb + (size_t)b * IMG;
        const _Float16* botg = botb + (size_t)b * IMG;

        half8v afr[2];
        #pragma unroll
        for (int kk = 0; kk < 2; ++kk)
            afr[kk] = *(const half8v*)&ceng[(size_t)(n0 + w * 16 + l16) * 64 + kk * 32 + quad * 8];

        int r0 = t >> 3, r1 = r0 + 32, off = (t & 7) * 8;
        int q2 = quad >> 1;
        int lpw = (w * 16 + quad * 4) * 72;
        int lpr = (w * 16 + l16) * 72;
        int rb3 = (l16 >> 3) & 1;

        f32x4 pv[4];
        #pragma unroll
        for (int j = 0; j < 4; ++j) pv[j] = (f32x4){0.f, 0.f, 0.f, 0.f};
        float runm = -3.0e38f, zacc = 0.f;

        int mp = s * 1024;
        half8v rt0 = *(const half8v*)&topg[(size_t)(mp + r0) * 64 + off];
        half8v rt1 = *(const half8v*)&topg[(size_t)(mp + r1) * 64 + off];
        half8v rb0 = *(const half8v*)&botg[(size_t)r0 * 4096 + mp + off];
        half8v rb1 = *(const half8v*)&botg[(size_t)r1 * 4096 + mp + off];

        for (int tt = 0; tt < 16; ++tt) {
            __syncthreads();
            *(half8v*)&ltop[r0 * 72 + off] = rt0;
            *(half8v*)&ltop[r1 * 72 + off] = rt1;
            *(half8v*)&lbot[r0 * 72 + off] = rb0;
            *(half8v*)&lbot[r1 * 72 + off] = rb1;
            __syncthreads();
            if (tt < 15) {
                int m1 = s * 1024 + (tt + 1) * 64;
                rt0 = *(const half8v*)&topg[(size_t)(m1 + r0) * 64 + off];
                rt1 = *(const half8v*)&topg[(size_t)(m1 + r1) * 64 + off];
                rb0 = *(const half8v*)&botg[(size_t)r0 * 4096 + m1 + off];
                rb1 = *(const half8v*)&botg[(size_t)r1 * 4096 + m1 + off];
            }
            f32x4 sa[4];
            #pragma unroll
            for (int j = 0; j < 4; ++j) sa[j] = (f32x4){0.f, 0.f, 0.f, 0.f};
            #pragma unroll
            for (int kk = 0; kk < 2; ++kk)
                #pragma unroll
                for (int j = 0; j < 4; ++j) {
                    half8v bfr = *(half8v*)&ltop[(j * 16 + l16) * 72 + kk * 32 + quad * 8];
                    sa[j] = __builtin_amdgcn_mfma_f32_16x16x32_f16(afr[kk], bfr, sa[j], 0, 0, 0);
                }
            float tm = -3.0e38f;
            #pragma unroll
            for (int j = 0; j < 4; ++j)
                #pragma unroll
                for (int r = 0; r < 4; ++r) tm = fmaxf(tm, sa[j][r]);
            for (int o2 = 32; o2; o2 >>= 1) tm = fmaxf(tm, __shfl_xor(tm, o2, 64));
            float newm = fmaxf(runm, tm);
            if (newm > runm) {
                float sc = exp2f(runm - newm);
                zacc *= sc;
                #pragma unroll
                for (int j = 0; j < 4; ++j) pv[j] *= sc;
                runm = newm;
            }
            #pragma unroll
            for (int j = 0; j < 4; ++j) {
                int cb2 = (j ^ q2) * 16 + l16;
                #pragma unroll
                for (int r = 0; r < 4; ++r) {
                    float e = exp2f(sa[j][r] - runm);
                    zacc += e;
                    lp[lpw + r * 72 + cb2] = (_Float16)e;
                }
            }
            half8v pa[2];
            #pragma unroll
            for (int kk = 0; kk < 2; ++kk) {
                int jj = kk * 2 + q2;
                pa[kk] = *(half8v*)&lp[lpr + ((jj ^ rb3) * 16) + (quad & 1) * 8];
            }
            #pragma unroll
            for (int kk = 0; kk < 2; ++kk)
                #pragma unroll
                for (int j = 0; j < 4; ++j) {
                    half8v bb2 = *(half8v*)&lbot[(j * 16 + l16) * 72 + kk * 32 + quad * 8];
                    pv[j] = __builtin_amdgcn_mfma_f32_16x16x32_f16(pa[kk], bb2, pv[j], 0, 0, 0);
                }
        }
        for (int o2 = 32; o2; o2 >>= 1) zacc += __shfl_xor(zacc, o2, 64);
        if (lane == 0) {
            ws[MSO + s * 1024 + b * 256 + st * 4 + w] = runm;
            ws[ZSO + s * 1024 + b * 256 + st * 4 + w] = zacc;
        }
        short* pvp = (short*)(ws + PVO) + (size_t)s * 1048576 + (size_t)b * IMG;
        #pragma unroll
        for (int j = 0; j < 4; ++j)
            #pragma unroll
            for (int r = 0; r < 4; ++r)
                pvp[(size_t)(n0 + w * 16 + quad * 4 + r) * 64 + j * 16 + l16] = f2bf(pv[j][r]);
    }
    gbar(bar + 128, t);

    // ======== Phase D: inline M/Z + u = x + softmax@bottom (short8 PV reads) +
    //                   u-powers (blocks 0..255) ========
    if (bx < 256) {
        float* us = (float*)smraw;
        float* rm = red8;
        float* rz = red8 + 4;
        int b = bx >> 6, h = bx & 63;
        float mv[4];
        float m = -3.0e38f;
        #pragma unroll
        for (int s = 0; s < 4; ++s) {
            mv[s] = ws[MSO + s * 1024 + b * 256 + t];
            m = fmaxf(m, mv[s]);
        }
        for (int o2 = 32; o2; o2 >>= 1) m = fmaxf(m, __shfl_xor(m, o2, 64));
        if ((t & 63) == 0) rm[t >> 6] = m;
        __syncthreads();
        float M = fmaxf(fmaxf(rm[0], rm[1]), fmaxf(rm[2], rm[3]));
        float z = 0.f;
        #pragma unroll
        for (int s = 0; s < 4; ++s)
            z += ws[ZSO + s * 1024 + b * 256 + t] * exp2f(mv[s] - M);
        for (int o2 = 32; o2; o2 >>= 1) z += __shfl_xor(z, o2, 64);
        if ((t & 63) == 0) rz[t >> 6] = z;
        __syncthreads();
        float Z = rz[0] + rz[1] + rz[2] + rz[3];

        const short* pvb = (const short*)(ws + PVO) + (size_t)b * IMG;
        int hg = h >> 4;
        #pragma unroll
        for (int it = 0; it < 2; ++it) {
            int idx = it * 2048 + t * 8;
            int ci = idx >> 6, wc = idx & 63;
            int rem = ci * 4096 + h * 64 + wc;
            int grp = ci * 4 + hg;
            float acc[8] = {};
            #pragma unroll
            for (int s = 0; s < MS; ++s) {
                float scl = exp2f(ws[MSO + s * 1024 + b * 256 + grp] - M);
                short8v pvv = *(const short8v*)&pvb[(size_t)s * 1048576 + rem];
                #pragma unroll
                for (int i = 0; i < 8; ++i) acc[i] += bf2f(pvv[i]) * scl;
            }
            float4 x0 = *(const float4*)&x[(size_t)b * IMG + rem];
            float4 x1 = *(const float4*)&x[(size_t)b * IMG + rem + 4];
            float xv[8] = {x0.x, x0.y, x0.z, x0.w, x1.x, x1.y, x1.z, x1.w};
            #pragma unroll
            for (int i = 0; i < 8; ++i)
                us[ci * 65 + wc + i] = xv[i] + acc[i] / Z;
        }
        __syncthreads();
        _Float16* dst = xpad + ((size_t)b * 6 * PADIMG + (h + 1) * 66 + 1) * 32;
        #pragma unroll
        for (int it = 0; it < 6; ++it) {
            int u = it * 256 + t;
            int ck = u >> 8, within = u & 255;
            int px = within >> 2, q = within & 3;
            int k0 = ck * 32 + q * 8;
            int p = k0 >> 6, c0 = k0 & 63;
            half8v o;
            #pragma unroll
            for (int j = 0; j < 8; ++j) {
                float v = us[(c0 + j) * 65 + px];
                float pw = (p == 0) ? v : ((p == 1) ? v * v : v * v * v);
                o[j] = (_Float16)pw;
            }
            *(half8v*)&dst[((size_t)ck * PADIMG + px) * 32 + q * 8] = o;
        }
    }
    gbar(bar + 192, t);

    // ======== Phase E: final 3x3 conv, direct fp32 output (blocks 0..511) ========
    if (bx < 512) {
        conv3d32(bx, t, xpad /* = upad */, wout, ob, nullptr, out);
    }
}

extern "C" void kernel_launch(void* const* d_in, const int* in_sizes, int n_in,
                              void* d_out, int out_size, void* d_ws, size_t ws_size,
                              hipStream_t stream) {
    (void)in_sizes; (void)n_in; (void)out_size; (void)ws_size;
    const float* x  = (const float*)d_in[0];
    const float* tw = (const float*)d_in[1];
    const float* tb = (const float*)d_in[2];
    const float* cw = (const float*)d_in[3];
    const float* cb = (const float*)d_in[4];
    const float* bw = (const float*)d_in[5];
    const float* bb = (const float*)d_in[6];
    const float* ow = (const float*)d_in[7];
    const float* ob = (const float*)d_in[8];
    float* ws  = (float*)d_ws;
    float* out = (float*)d_out;

    // zero the 4 grid-barrier counters (re-poisoned 0xAA before every replay)
    hipMemsetAsync(ws + BARO, 0, 4 * 64 * sizeof(unsigned), stream);
    hipLaunchKernelGGL(k_mega, dim3(1024), dim3(256), 0, stream,
                       bw, ow, tw, cw, tb, cb, bb, ob, x, ws, out);
}

// Round 17
// 165.865 us; speedup vs baseline: 6.7841x; 6.7841x over previous
//
#include <hip/hip_runtime.h>
#include <hip/hip_bf16.h>

// Problem constants: B=4, C=64, H=W=64, HW=4096, P=64, Q=3 (CQ=192)
namespace {
constexpr int IMG    = 262144;   // 64*4096 elems per batch image
constexpr int MS     = 4;        // attention m-split
constexpr int PADIMG = 4356;     // 66*66 padded pixels
constexpr float LOG2E = 1.44269504088896340736f;
// workspace float offsets
constexpr int WBFO  = 0;         // fp16 weights: wbot[9][6][64][32], wout[9][6][64][32], wtop[6][64][32], wcen[6][64][32]
constexpr int XPADO = 122880;    // fp16 xp/up padded [b][ck 6][px 4356][32] (aliased: xp then up)
constexpr int TOPO  = 1795584;   // fp16 topT [b][m][p]
constexpr int CENO  = 2319872;   // fp16 cenT [b][n][p]
constexpr int BOTO  = 2844160;   // fp16 bot  [b][c][m]
constexpr int PVO   = 3368448;   // bf16 PV [4][b][n][c]
constexpr int MSO   = 5465600;   // m_s [s 4][b 4][group 128]  (group = 32-row n-group)
constexpr int ZSO   = 5467648;   // z_s  (MSO + 2048)
}

using half8v  = __attribute__((ext_vector_type(8))) _Float16;
using half4v  = __attribute__((ext_vector_type(4))) _Float16;
using short8v = __attribute__((ext_vector_type(8))) short;
typedef __attribute__((ext_vector_type(4))) float f32x4;

__device__ __forceinline__ short f2bf(float f) {
    __hip_bfloat16 h = __float2bfloat16(f);
    return *reinterpret_cast<short*>(&h);
}
__device__ __forceinline__ float bf2f(short s) {
    unsigned u = ((unsigned)(unsigned short)s) << 16;
    return __uint_as_float(u);
}

// ---- Dispatch 1: weights->fp16 reorder into k-chunked layouts (blocks 0..959)
// + x-powers into chunked padded xpad incl. border zeroing (blocks 960..1215).
__global__ __launch_bounds__(256) void k_prep(const float* __restrict__ bw, const float* __restrict__ ow,
                                              const float* __restrict__ tw, const float* __restrict__ cw,
                                              _Float16* __restrict__ wbf,
                                              const float* __restrict__ x, _Float16* __restrict__ xpad) {
    __shared__ float xs[64 * 65];
    int bx = blockIdx.x, t = threadIdx.x;
    if (bx < 960) {
        int idx = bx * 256 + t;   // < 245760
        if (idx < 221184) {
            // 3x3: w[o][(p*64+ci)*9+tap] -> wT[tap][ck][o][ki]  (k = ck*32+ki = p*64+ci)
            int tsel = idx / 110592;
            int r    = idx - tsel * 110592;
            int tap  = r / 12288;
            int rr   = r - tap * 12288;
            int ck   = rr / 2048;
            int r2   = rr - ck * 2048;
            int o    = r2 >> 5;
            int ki   = r2 & 31;
            int k    = ck * 32 + ki;
            int p    = k >> 6, ci = k & 63;
            const float* src = tsel ? ow : bw;
            wbf[idx] = (_Float16)src[o * 1728 + (p * 64 + ci) * 9 + tap];
        } else {
            // 1x1: w[o][192] -> wT[ck][o][ki]; center pre-scaled by log2(e)
            int j = idx - 221184;
            int tsel = j / 12288;
            int rr   = j - tsel * 12288;
            int ck   = rr / 2048;
            int r2   = rr - ck * 2048;
            int o    = r2 >> 5;
            int ki   = r2 & 31;
            int k    = ck * 32 + ki;
            wbf[idx] = (_Float16)(tsel ? cw[o * 192 + k] * LOG2E : tw[o * 192 + k]);
        }
        return;
    }
    int bx2 = bx - 960;
    int b = bx2 >> 6, h = bx2 & 63;
    // zero this block's share of the pad border across all 6 chunk planes
    {
        _Float16* base = xpad + (size_t)b * 6 * PADIMG * 32;
        int px[6];
        px[0] = (h + 1) * 66;
        px[1] = (h + 1) * 66 + 65;
        px[2] = h;
        px[3] = 65 * 66 + h;
        int npx = 4;
        if (h < 2) { px[4] = 64 + h; px[5] = 65 * 66 + 64 + h; npx = 6; }
        int pi = t / 24, ck = t % 24;
        if (pi < npx) {
            int cp = ck >> 2, q = ck & 3;
            half8v z = {0, 0, 0, 0, 0, 0, 0, 0};
            *(half8v*)&base[((size_t)cp * PADIMG + px[pi]) * 32 + q * 8] = z;
        }
    }
    #pragma unroll
    for (int it = 0; it < 16; ++it) {
        int idx = it * 256 + t;
        int ci = idx >> 6, wc = idx & 63;
        xs[ci * 65 + wc] = x[b * IMG + ci * 4096 + h * 64 + wc];
    }
    __syncthreads();
    _Float16* dst = xpad + ((size_t)b * 6 * PADIMG + (h + 1) * 66 + 1) * 32;
    #pragma unroll
    for (int it = 0; it < 6; ++it) {
        int u = it * 256 + t;
        int ck = u >> 8, within = u & 255;
        int px = within >> 2, q = within & 3;
        int k0 = ck * 32 + q * 8;
        int p = k0 >> 6, c0 = k0 & 63;
        half8v o;
        #pragma unroll
        for (int j = 0; j < 8; ++j) {
            float v = xs[(c0 + j) * 65 + px];
            float pw = (p == 0) ? v : ((p == 1) ? v * v : v * v * v);
            o[j] = (_Float16)pw;
        }
        *(half8v*)&dst[((size_t)ck * PADIMG + px) * 32 + q * 8] = o;
    }
}

// 3x3 SelfONN conv, full-K MFMA implicit GEMM, 32 oc/block, direct output+bias.
__device__ __forceinline__ void conv3d32(int bx, int t,
                                         const _Float16* __restrict__ src,
                                         const _Float16* __restrict__ wt,
                                         const float* __restrict__ bias,
                                         _Float16* __restrict__ dh_, float* __restrict__ df) {
    int lane = t & 63, w = t >> 6;
    int l16 = lane & 15, quad = lane >> 4;
    int oh = bx >> 8, mt = bx & 255;
    int b = mt >> 6, h = mt & 63;
    const _Float16* abase = src + ((size_t)b * 6 * PADIMG + (h + 1) * 66 + 1 + w * 16 + l16) * 32 + quad * 8;
    const _Float16* bbase = wt + (size_t)(oh * 32 + l16) * 32 + quad * 8;
    f32x4 acc[2];
    acc[0] = (f32x4){0.f, 0.f, 0.f, 0.f};
    acc[1] = (f32x4){0.f, 0.f, 0.f, 0.f};
    for (int tap = 0; tap < 9; ++tap) {
        int dh = tap / 3 - 1, dw = tap % 3 - 1;
        const _Float16* arow = abase + (dh * 66 + dw) * 32;
        const _Float16* brow = bbase + (size_t)tap * 6 * 2048;
        #pragma unroll
        for (int c6 = 0; c6 < 6; ++c6) {
            half8v afr  = *(const half8v*)&arow[(size_t)c6 * PADIMG * 32];
            half8v bfr0 = *(const half8v*)&brow[(size_t)c6 * 2048];
            half8v bfr1 = *(const half8v*)&brow[(size_t)c6 * 2048 + 512];
            acc[0] = __builtin_amdgcn_mfma_f32_16x16x32_f16(afr, bfr0, acc[0], 0, 0, 0);
            acc[1] = __builtin_amdgcn_mfma_f32_16x16x32_f16(afr, bfr1, acc[1], 0, 0, 0);
        }
    }
    #pragma unroll
    for (int nf = 0; nf < 2; ++nf) {
        int c = oh * 32 + nf * 16 + l16;
        float bv = bias[c];
        size_t oi = (size_t)b * 262144 + (size_t)c * 4096 + h * 64 + w * 16 + quad * 4;
        if (dh_) {
            half4v o;
            #pragma unroll
            for (int r = 0; r < 4; ++r) o[r] = (_Float16)(acc[nf][r] + bv);
            *(half4v*)&dh_[oi] = o;
        } else {
            float4 o = make_float4(acc[nf][0] + bv, acc[nf][1] + bv, acc[nf][2] + bv, acc[nf][3] + bv);
            *(float4*)&df[oi] = o;
        }
    }
}

// ---- Dispatch 2: conv3-bottom (blocks 0..511, direct fp16 out, oc-32) + fused
// top/center 1x1 convs (blocks 512..1023).
__global__ __launch_bounds__(256) void k_convs(const _Float16* __restrict__ xpad,
                                               const _Float16* __restrict__ wbf,
                                               const float* __restrict__ tb, const float* __restrict__ cb,
                                               const float* __restrict__ bbias,
                                               _Float16* __restrict__ topd, _Float16* __restrict__ cend,
                                               _Float16* __restrict__ botb) {
    int bx = blockIdx.x, t = threadIdx.x;
    if (bx < 512) {
        conv3d32(bx, t, xpad, wbf /* wbot at offset 0 */, bbias, botb, nullptr);
        return;
    }
    int bx2 = bx - 512;
    int lane = t & 63, w = t >> 6;
    int l16 = lane & 15, quad = lane >> 4;
    int ot = bx2 >> 8, mt = bx2 & 255;
    int b = mt >> 6, h = mt & 63;
    const _Float16* wt   = wbf + (ot ? 233472 : 221184);   // wcen : wtop
    const float*    bias = ot ? cb : tb;
    _Float16*       dst  = (ot ? cend : topd) + (size_t)b * IMG;
    const _Float16* abase = xpad + ((size_t)b * 6 * PADIMG + (h + 1) * 66 + 1 + w * 16 + l16) * 32 + quad * 8;
    const _Float16* bbase = wt + (size_t)l16 * 32 + quad * 8;
    f32x4 acc[4];
    #pragma unroll
    for (int nf = 0; nf < 4; ++nf) acc[nf] = (f32x4){0.f, 0.f, 0.f, 0.f};
    #pragma unroll
    for (int kc = 0; kc < 6; ++kc) {
        half8v afr = *(const half8v*)&abase[(size_t)kc * PADIMG * 32];
        #pragma unroll
        for (int nf = 0; nf < 4; ++nf) {
            half8v bfr = *(const half8v*)&bbase[(size_t)kc * 2048 + nf * 16 * 32];
            acc[nf] = __builtin_amdgcn_mfma_f32_16x16x32_f16(afr, bfr, acc[nf], 0, 0, 0);
        }
    }
    _Float16* dp = dst + (size_t)(h * 64 + w * 16) * 64;
    #pragma unroll
    for (int nf = 0; nf < 4; ++nf) {
        float bv = bias[nf * 16 + l16];
        if (ot) bv *= LOG2E;   // center output lives in log2e-scaled domain
        #pragma unroll
        for (int r = 0; r < 4; ++r)
            dp[(quad * 4 + r) * 64 + nf * 16 + l16] = (_Float16)(acc[nf][r] + bv);
    }
}

// ---- Dispatch 3: fp16 MFMA flash attention, global softmax, per-wave online max.
// 32 n-rows per wave (2x16-row frags) -> LDS cycles per MFMA drop 22.5 -> 15.
// LDS staging for ltop+lbot (cross-wave reuse) + register prefetch pipeline;
// lp wave-private + XOR swizzle. grid 512: (strip 32 of 128 rows) x (b 4) x (split 4).
__global__ __launch_bounds__(256) void k_attn(float* __restrict__ ws) {
    __shared__ _Float16 ltop[64 * 72];    // [m][p]
    __shared__ _Float16 lbot[64 * 72];    // [c][m]
    __shared__ _Float16 lp[128 * 72];     // [n][m swizzled]; wave-private rows
    int t    = threadIdx.x;
    int lane = t & 63, w = t >> 6;
    int l16  = lane & 15, quad = lane >> 4;
    int bx = blockIdx.x;
    int st = bx & 31, b = (bx >> 5) & 3, s = bx >> 7;
    int n0 = st * 128;
    const _Float16* topg = (const _Float16*)(ws + TOPO) + (size_t)b * IMG;
    const _Float16* ceng = (const _Float16*)(ws + CENO) + (size_t)b * IMG;
    const _Float16* botg = (const _Float16*)(ws + BOTO) + (size_t)b * IMG;

    half8v afr[2][2];   // [row-frag i][kk]
    #pragma unroll
    for (int i = 0; i < 2; ++i)
        #pragma unroll
        for (int kk = 0; kk < 2; ++kk)
            afr[i][kk] = *(const half8v*)&ceng[(size_t)(n0 + w * 32 + i * 16 + l16) * 64 + kk * 32 + quad * 8];

    int r0 = t >> 3, r1 = r0 + 32, off = (t & 7) * 8;
    int q2 = quad >> 1;
    int lpw = (w * 32 + quad * 4) * 72;   // + i*1152 (16 rows) + r*72
    int lpr = (w * 32 + l16) * 72;        // + i*1152
    int rb3 = (l16 >> 3) & 1;

    f32x4 pv[2][4];
    #pragma unroll
    for (int i = 0; i < 2; ++i)
        #pragma unroll
        for (int j = 0; j < 4; ++j) pv[i][j] = (f32x4){0.f, 0.f, 0.f, 0.f};
    float runm = -3.0e38f, zacc = 0.f;

    int mp = s * 1024;
    half8v rt0 = *(const half8v*)&topg[(size_t)(mp + r0) * 64 + off];
    half8v rt1 = *(const half8v*)&topg[(size_t)(mp + r1) * 64 + off];
    half8v rb0 = *(const half8v*)&botg[(size_t)r0 * 4096 + mp + off];
    half8v rb1 = *(const half8v*)&botg[(size_t)r1 * 4096 + mp + off];

    for (int tt = 0; tt < 16; ++tt) {
        __syncthreads();
        *(half8v*)&ltop[r0 * 72 + off] = rt0;
        *(half8v*)&ltop[r1 * 72 + off] = rt1;
        *(half8v*)&lbot[r0 * 72 + off] = rb0;
        *(half8v*)&lbot[r1 * 72 + off] = rb1;
        __syncthreads();
        if (tt < 15) {
            int m1 = s * 1024 + (tt + 1) * 64;
            rt0 = *(const half8v*)&topg[(size_t)(m1 + r0) * 64 + off];
            rt1 = *(const half8v*)&topg[(size_t)(m1 + r1) * 64 + off];
            rb0 = *(const half8v*)&botg[(size_t)r0 * 4096 + m1 + off];
            rb1 = *(const half8v*)&botg[(size_t)r1 * 4096 + m1 + off];
        }
        // S = cen * top: 16 MFMAs, 8 ltop reads (bfr reused across row-frags)
        f32x4 sa[2][4];
        #pragma unroll
        for (int i = 0; i < 2; ++i)
            #pragma unroll
            for (int j = 0; j < 4; ++j) sa[i][j] = (f32x4){0.f, 0.f, 0.f, 0.f};
        #pragma unroll
        for (int kk = 0; kk < 2; ++kk)
            #pragma unroll
            for (int j = 0; j < 4; ++j) {
                half8v bfr = *(half8v*)&ltop[(j * 16 + l16) * 72 + kk * 32 + quad * 8];
                sa[0][j] = __builtin_amdgcn_mfma_f32_16x16x32_f16(afr[0][kk], bfr, sa[0][j], 0, 0, 0);
                sa[1][j] = __builtin_amdgcn_mfma_f32_16x16x32_f16(afr[1][kk], bfr, sa[1][j], 0, 0, 0);
            }
        float tm = -3.0e38f;
        #pragma unroll
        for (int i = 0; i < 2; ++i)
            #pragma unroll
            for (int j = 0; j < 4; ++j)
                #pragma unroll
                for (int r = 0; r < 4; ++r) tm = fmaxf(tm, sa[i][j][r]);
        for (int o2 = 32; o2; o2 >>= 1) tm = fmaxf(tm, __shfl_xor(tm, o2, 64));
        float newm = fmaxf(runm, tm);
        if (newm > runm) {
            float sc = exp2f(runm - newm);
            zacc *= sc;
            #pragma unroll
            for (int i = 0; i < 2; ++i)
                #pragma unroll
                for (int j = 0; j < 4; ++j) pv[i][j] *= sc;
            runm = newm;
        }
        // exp2 + swizzled P writes (wave-private 32 rows, two 16-row groups)
        #pragma unroll
        for (int i = 0; i < 2; ++i)
            #pragma unroll
            for (int j = 0; j < 4; ++j) {
                int cb = (j ^ q2) * 16 + l16;
                #pragma unroll
                for (int r = 0; r < 4; ++r) {
                    float e = exp2f(sa[i][j][r] - runm);
                    zacc += e;
                    lp[lpw + i * 1152 + r * 72 + cb] = (_Float16)e;
                }
            }
        // P A-frags back (4 reads) + PV: 16 MFMAs, 8 lbot reads (bb reused)
        half8v pa[2][2];
        #pragma unroll
        for (int i = 0; i < 2; ++i)
            #pragma unroll
            for (int kk = 0; kk < 2; ++kk) {
                int jj = kk * 2 + q2;
                pa[i][kk] = *(half8v*)&lp[lpr + i * 1152 + ((jj ^ rb3) * 16) + (quad & 1) * 8];
            }
        #pragma unroll
        for (int kk = 0; kk < 2; ++kk)
            #pragma unroll
            for (int j = 0; j < 4; ++j) {
                half8v bb = *(half8v*)&lbot[(j * 16 + l16) * 72 + kk * 32 + quad * 8];
                pv[0][j] = __builtin_amdgcn_mfma_f32_16x16x32_f16(pa[0][kk], bb, pv[0][j], 0, 0, 0);
                pv[1][j] = __builtin_amdgcn_mfma_f32_16x16x32_f16(pa[1][kk], bb, pv[1][j], 0, 0, 0);
            }
    }
    for (int o2 = 32; o2; o2 >>= 1) zacc += __shfl_xor(zacc, o2, 64);
    if (lane == 0) {
        ws[MSO + s * 512 + b * 128 + st * 4 + w] = runm;
        ws[ZSO + s * 512 + b * 128 + st * 4 + w] = zacc;
    }
    short* pvp = (short*)(ws + PVO) + (size_t)s * 1048576 + (size_t)b * IMG;
    #pragma unroll
    for (int i = 0; i < 2; ++i)
        #pragma unroll
        for (int j = 0; j < 4; ++j)
            #pragma unroll
            for (int r = 0; r < 4; ++r)
                pvp[(size_t)(n0 + w * 32 + i * 16 + quad * 4 + r) * 64 + j * 16 + l16] = f2bf(pv[i][j][r]);
}

// ---- Dispatch 4: inline M/Z reduction (128 32-row groups/b) + u = x +
// softmax@bottom (short8 PV reads) + u-powers -> chunked padded fp16.
__global__ __launch_bounds__(256) void k_finalu(const float* __restrict__ x, float* __restrict__ ws,
                                                _Float16* __restrict__ upad) {
    __shared__ float us[64 * 65];
    __shared__ float rm[4], rz[4];
    int t = threadIdx.x, bx = blockIdx.x;
    int b = bx >> 6, h = bx & 63;
    int g = t & 127;   // group index (duplicated across upper half; z guarded)
    float mv[4];
    float m = -3.0e38f;
    #pragma unroll
    for (int s = 0; s < 4; ++s) {
        mv[s] = ws[MSO + s * 512 + b * 128 + g];
        m = fmaxf(m, mv[s]);
    }
    for (int o2 = 32; o2; o2 >>= 1) m = fmaxf(m, __shfl_xor(m, o2, 64));
    if ((t & 63) == 0) rm[t >> 6] = m;
    __syncthreads();
    float M = fmaxf(fmaxf(rm[0], rm[1]), fmaxf(rm[2], rm[3]));
    float z = 0.f;
    if (t < 128) {
        #pragma unroll
        for (int s = 0; s < 4; ++s)
            z += ws[ZSO + s * 512 + b * 128 + g] * exp2f(mv[s] - M);
    }
    for (int o2 = 32; o2; o2 >>= 1) z += __shfl_xor(z, o2, 64);
    if ((t & 63) == 0) rz[t >> 6] = z;
    __syncthreads();
    float Z = rz[0] + rz[1] + rz[2] + rz[3];

    const short* pvb = (const short*)(ws + PVO) + (size_t)b * IMG;
    int hg = h >> 5;
    #pragma unroll
    for (int it = 0; it < 2; ++it) {
        int idx = it * 2048 + t * 8;      // 8 consecutive wc per thread
        int ci = idx >> 6, wc = idx & 63;
        int rem = ci * 4096 + h * 64 + wc;
        int grp = ci * 2 + hg;            // n = ci*64+h; 32-row group = n>>5
        float acc[8] = {};
        #pragma unroll
        for (int s = 0; s < MS; ++s) {
            float scl = exp2f(ws[MSO + s * 512 + b * 128 + grp] - M);
            short8v pvv = *(const short8v*)&pvb[(size_t)s * 1048576 + rem];
            #pragma unroll
            for (int i = 0; i < 8; ++i) acc[i] += bf2f(pvv[i]) * scl;
        }
        float4 x0 = *(const float4*)&x[(size_t)b * IMG + rem];
        float4 x1 = *(const float4*)&x[(size_t)b * IMG + rem + 4];
        float xv[8] = {x0.x, x0.y, x0.z, x0.w, x1.x, x1.y, x1.z, x1.w};
        #pragma unroll
        for (int i = 0; i < 8; ++i)
            us[ci * 65 + wc + i] = xv[i] + acc[i] / Z;
    }
    __syncthreads();
    _Float16* dst = upad + ((size_t)b * 6 * PADIMG + (h + 1) * 66 + 1) * 32;
    #pragma unroll
    for (int it = 0; it < 6; ++it) {
        int u = it * 256 + t;
        int ck = u >> 8, within = u & 255;
        int px = within >> 2, q = within & 3;
        int k0 = ck * 32 + q * 8;
        int p = k0 >> 6, c0 = k0 & 63;
        half8v o;
        #pragma unroll
        for (int j = 0; j < 8; ++j) {
            float v = us[(c0 + j) * 65 + px];
            float pw = (p == 0) ? v : ((p == 1) ? v * v : v * v * v);
            o[j] = (_Float16)pw;
        }
        *(half8v*)&dst[((size_t)ck * PADIMG + px) * 32 + q * 8] = o;
    }
}

// ---- Dispatch 5: final 3x3 conv, direct fp32 output + bias, oc-32. grid 512.
__global__ __launch_bounds__(256) void k_conv3o(const _Float16* __restrict__ upad,
                                                const _Float16* __restrict__ wout,
                                                const float* __restrict__ ob,
                                                float* __restrict__ out) {
    conv3d32(blockIdx.x, threadIdx.x, upad, wout, ob, nullptr, out);
}

extern "C" void kernel_launch(void* const* d_in, const int* in_sizes, int n_in,
                              void* d_out, int out_size, void* d_ws, size_t ws_size,
                              hipStream_t stream) {
    (void)in_sizes; (void)n_in; (void)out_size; (void)ws_size;
    const float* x  = (const float*)d_in[0];
    const float* tw = (const float*)d_in[1];
    const float* tb = (const float*)d_in[2];
    const float* cw = (const float*)d_in[3];
    const float* cb = (const float*)d_in[4];
    const float* bw = (const float*)d_in[5];
    const float* bb = (const float*)d_in[6];
    const float* ow = (const float*)d_in[7];
    const float* ob = (const float*)d_in[8];
    float* ws  = (float*)d_ws;
    float* out = (float*)d_out;

    _Float16* wbf  = (_Float16*)(ws + WBFO);
    _Float16* wout = wbf + 110592;
    _Float16* xpad = (_Float16*)(ws + XPADO);   // also upad (aliased)
    _Float16* topb = (_Float16*)(ws + TOPO);
    _Float16* cenb = (_Float16*)(ws + CENO);
    _Float16* botb = (_Float16*)(ws + BOTO);

    hipLaunchKernelGGL(k_prep, dim3(1216), dim3(256), 0, stream, bw, ow, tw, cw, wbf, x, xpad);
    hipLaunchKernelGGL(k_convs, dim3(1024), dim3(256), 0, stream, xpad, wbf, tb, cb, bb, topb, cenb, botb);
    hipLaunchKernelGGL(k_attn, dim3(512), dim3(256), 0, stream, ws);
    hipLaunchKernelGGL(k_finalu, dim3(256), dim3(256), 0, stream, x, ws, xpad);
    hipLaunchKernelGGL(k_conv3o, dim3(512), dim3(256), 0, stream, xpad, wout, ob, out);
}